// Round 1
// baseline (277.492 us; speedup 1.0000x reference)
//
#include <hip/hip_runtime.h>

typedef unsigned short u16;
typedef __bf16 bf16x8 __attribute__((ext_vector_type(8)));
typedef float f32x4 __attribute__((ext_vector_type(4)));

#define LOG2E 1.44269504088896340736f

constexpr int Bc = 2, Nc = 2048, Cch = 1024, Hh = 16, Dd = 64;
constexpr int Mrows = Bc * Nc;        // 4096
constexpr int N_QKV = 3 * Cch;        // 3072

__device__ __forceinline__ u16 f2bf(float f) {
  unsigned int u = __float_as_uint(f);
  u += 0x7fffu + ((u >> 16) & 1u);
  return (u16)(u >> 16);
}

__device__ __forceinline__ void gload16(const void* g, void* l) {
  __builtin_amdgcn_global_load_lds((const __attribute__((address_space(1))) void*)g,
                                   (__attribute__((address_space(3))) void*)l, 16, 0, 0);
}

#define MFMA(a, b, c) __builtin_amdgcn_mfma_f32_16x16x32_bf16(a, b, c, 0, 0, 0)

// ---------------- cast x (fp32 -> bf16), 4 elems/thread ----------------
__global__ __launch_bounds__(256) void cast_x_kernel(const float* __restrict__ in,
                                                     u16* __restrict__ out, int n4) {
  int i = blockIdx.x * 256 + threadIdx.x;
  if (i >= n4) return;
  float4 v = *(const float4*)&in[i * 4];
  union { u16 h[4]; short4 s; } u;
  u.h[0] = f2bf(v.x); u.h[1] = f2bf(v.y); u.h[2] = f2bf(v.z); u.h[3] = f2bf(v.w);
  *(short4*)&out[i * 4] = u.s;
}

// ------------- transpose + cast: in fp32 [R][Cq] -> out bf16 [Cq][R] -------------
__global__ __launch_bounds__(256) void transpose_cast_kernel(const float* __restrict__ in,
                                                             u16* __restrict__ out,
                                                             int R, int Cq) {
  __shared__ float tile[32][33];
  int bx = blockIdx.x * 32;  // col base in input
  int by = blockIdx.y * 32;  // row base in input
  int tx = threadIdx.x & 31, ty = threadIdx.x >> 5;  // 32 x 8
#pragma unroll
  for (int i = 0; i < 32; i += 8)
    tile[ty + i][tx] = in[(size_t)(by + ty + i) * Cq + bx + tx];
  __syncthreads();
#pragma unroll
  for (int i = 0; i < 32; i += 8)
    out[(size_t)(bx + ty + i) * R + by + tx] = f2bf(tile[tx][ty + i]);
}

// ---------------- QKV GEMM: Xb[4096,1024] @ W1T[3072,1024]^T + b -> Q/K/Vt ----------------
__global__ __launch_bounds__(256) void gemm_qkv_kernel(const u16* __restrict__ A,
                                                       const u16* __restrict__ Bt,
                                                       const float* __restrict__ bias,
                                                       u16* __restrict__ Qo,
                                                       u16* __restrict__ Ko,
                                                       u16* __restrict__ Vto) {
  __shared__ u16 As[128 * 32];
  __shared__ u16 Bs[128 * 32];
  f32x4 acc[4][4] = {};
  int tid = threadIdx.x, lane = tid & 63, wid = tid >> 6;
  int wr = wid >> 1, wc = wid & 1;
  int l15 = lane & 15, g = lane >> 4;
  int rowBase = blockIdx.x * 128, colBase = blockIdx.y * 128;
  int rowS = tid >> 2, c8 = (tid & 3) << 3;

  for (int k0 = 0; k0 < 1024; k0 += 32) {
    __syncthreads();
    gload16(&A[(size_t)(rowBase + rowS) * 1024 + k0 + c8],        (char*)As + wid * 1024);
    gload16(&A[(size_t)(rowBase + 64 + rowS) * 1024 + k0 + c8],   (char*)As + 4096 + wid * 1024);
    gload16(&Bt[(size_t)(colBase + rowS) * 1024 + k0 + c8],       (char*)Bs + wid * 1024);
    gload16(&Bt[(size_t)(colBase + 64 + rowS) * 1024 + k0 + c8],  (char*)Bs + 4096 + wid * 1024);
    __syncthreads();
    bf16x8 af[4], bfv[4];
#pragma unroll
    for (int m = 0; m < 4; ++m)
      af[m] = *(const bf16x8*)&As[(wr * 64 + m * 16 + l15) * 32 + g * 8];
#pragma unroll
    for (int n = 0; n < 4; ++n)
      bfv[n] = *(const bf16x8*)&Bs[(wc * 64 + n * 16 + l15) * 32 + g * 8];
#pragma unroll
    for (int m = 0; m < 4; ++m)
#pragma unroll
      for (int n = 0; n < 4; ++n)
        acc[m][n] = MFMA(af[m], bfv[n], acc[m][n]);
  }

  // epilogue: scatter to Q [bh,n,d], K [bh,n,d], V^T [bh,d,n]  (bf16)
#pragma unroll
  for (int m = 0; m < 4; ++m)
#pragma unroll
    for (int n = 0; n < 4; ++n) {
      int colc = colBase + wc * 64 + n * 16 + l15;
      float bv = bias[colc];
      int s = colc >> 10, hd = colc & 1023;
      int h = hd >> 6, d = hd & 63;
#pragma unroll
      for (int j = 0; j < 4; ++j) {
        int r = rowBase + wr * 64 + m * 16 + g * 4 + j;
        int b = r >> 11, nn = r & 2047;
        u16 v = f2bf(acc[m][n][j] + bv);
        size_t bh = (size_t)(b * 16 + h);
        if (s == 0)      Qo[(bh * 2048 + nn) * 64 + d] = v;
        else if (s == 1) Ko[(bh * 2048 + nn) * 64 + d] = v;
        else             Vto[(bh * 64 + d) * 2048 + nn] = v;
      }
    }
}

// ---------------- flash attention: per (q-tile, bh) block ----------------
__global__ __launch_bounds__(256) void attn_kernel(const u16* __restrict__ Q,
                                                   const u16* __restrict__ Km,
                                                   const u16* __restrict__ Vt,
                                                   u16* __restrict__ AO) {
  __shared__ u16 Ks[64 * 72];
  __shared__ u16 Vs[64 * 72];
  __shared__ u16 Ps[128 * 72];
  int tid = threadIdx.x, lane = tid & 63, w = tid >> 6;
  int l15 = lane & 15, g = lane >> 4;
  int qt = blockIdx.x, bh = blockIdx.y;
  int b = bh >> 4, h = bh & 15;
  const size_t base = (size_t)bh * 2048 * 64;  // same for Q/K ([bh,n,d]) and Vt ([bh,d,n])
  int qrow0 = qt * 128 + w * 32;

  bf16x8 qf[2][2];
#pragma unroll
  for (int mm = 0; mm < 2; ++mm)
#pragma unroll
    for (int ks = 0; ks < 2; ++ks)
      qf[mm][ks] = *(const bf16x8*)&Q[base + (size_t)(qrow0 + mm * 16 + l15) * 64 + ks * 32 + g * 8];

  f32x4 o[2][4] = {};
  float m_run[2][4], l_run[2][4];
#pragma unroll
  for (int mm = 0; mm < 2; ++mm)
#pragma unroll
    for (int j = 0; j < 4; ++j) { m_run[mm][j] = -1e30f; l_run[mm][j] = 0.f; }

  for (int nk0 = 0; nk0 < 2048; nk0 += 64) {
    // stage K tile [64 rows n'][64 d] and V^T tile [64 rows d][64 n'] (both padded to 72)
#pragma unroll
    for (int it = 0; it < 2; ++it) {
      int c = tid + it * 256;
      int rr = c >> 3, cc = (c & 7) * 8;
      *(int4*)&Ks[rr * 72 + cc] = *(const int4*)&Km[base + (size_t)(nk0 + rr) * 64 + cc];
      *(int4*)&Vs[rr * 72 + cc] = *(const int4*)&Vt[base + (size_t)rr * 2048 + nk0 + cc];
    }
    __syncthreads();

    // S = Q K^T  (rows: 32 per wave; cols: 64 kv)
    f32x4 s[2][4] = {};
#pragma unroll
    for (int ks = 0; ks < 2; ++ks) {
      bf16x8 kf[4];
#pragma unroll
      for (int n = 0; n < 4; ++n)
        kf[n] = *(const bf16x8*)&Ks[(n * 16 + l15) * 72 + ks * 32 + g * 8];
#pragma unroll
      for (int mm = 0; mm < 2; ++mm)
#pragma unroll
        for (int n = 0; n < 4; ++n)
          s[mm][n] = MFMA(qf[mm][ks], kf[n], s[mm][n]);
    }

    // online softmax (scale = 1/8)
#pragma unroll
    for (int mm = 0; mm < 2; ++mm)
#pragma unroll
      for (int j = 0; j < 4; ++j) {
        float v = fmaxf(fmaxf(s[mm][0][j], s[mm][1][j]), fmaxf(s[mm][2][j], s[mm][3][j]));
        v = fmaxf(v, __shfl_xor(v, 1));
        v = fmaxf(v, __shfl_xor(v, 2));
        v = fmaxf(v, __shfl_xor(v, 4));
        v = fmaxf(v, __shfl_xor(v, 8));
        v *= 0.125f;
        float mold = m_run[mm][j];
        float mnew = fmaxf(mold, v);
        float alpha = exp2f((mold - mnew) * LOG2E);
        m_run[mm][j] = mnew;
        float rsum = 0.f;
#pragma unroll
        for (int n = 0; n < 4; ++n) {
          float p = exp2f((s[mm][n][j] * 0.125f - mnew) * LOG2E);
          s[mm][n][j] = p;
          rsum += p;
        }
        rsum += __shfl_xor(rsum, 1);
        rsum += __shfl_xor(rsum, 2);
        rsum += __shfl_xor(rsum, 4);
        rsum += __shfl_xor(rsum, 8);
        l_run[mm][j] = l_run[mm][j] * alpha + rsum;
#pragma unroll
        for (int n = 0; n < 4; ++n) o[mm][n][j] *= alpha;
      }

    // P (C-frag layout) -> LDS bf16 (per-wave private 32-row band)
#pragma unroll
    for (int mm = 0; mm < 2; ++mm)
#pragma unroll
      for (int n = 0; n < 4; ++n)
#pragma unroll
        for (int j = 0; j < 4; ++j)
          Ps[(w * 32 + mm * 16 + g * 4 + j) * 72 + n * 16 + l15] = f2bf(s[mm][n][j]);

    // O += P @ V   (same-wave LDS RAW: compiler inserts lgkmcnt)
#pragma unroll
    for (int ks = 0; ks < 2; ++ks) {
      bf16x8 pa[2];
#pragma unroll
      for (int mm = 0; mm < 2; ++mm)
        pa[mm] = *(const bf16x8*)&Ps[(w * 32 + mm * 16 + l15) * 72 + ks * 32 + g * 8];
#pragma unroll
      for (int dn = 0; dn < 4; ++dn) {
        bf16x8 vb = *(const bf16x8*)&Vs[(dn * 16 + l15) * 72 + ks * 32 + g * 8];
#pragma unroll
        for (int mm = 0; mm < 2; ++mm)
          o[mm][dn] = MFMA(pa[mm], vb, o[mm][dn]);
      }
    }
    __syncthreads();
  }

  // epilogue: AO[b*2048+n][h*64+d]  (row-major [4096][1024] bf16)
#pragma unroll
  for (int mm = 0; mm < 2; ++mm)
#pragma unroll
    for (int j = 0; j < 4; ++j) {
      float inv = 1.0f / l_run[mm][j];
      int nq = qrow0 + mm * 16 + g * 4 + j;
      size_t rowb = ((size_t)b * 2048 + nq) * 1024 + h * 64;
#pragma unroll
      for (int dn = 0; dn < 4; ++dn)
        AO[rowb + dn * 16 + l15] = f2bf(o[mm][dn][j] * inv);
    }
}

// ---------------- output GEMM: AO[4096,1024] @ W2T[1024,1024]^T + b -> fp32 out ----------------
__global__ __launch_bounds__(256) void gemm_proj_kernel(const u16* __restrict__ A,
                                                        const u16* __restrict__ Bt,
                                                        const float* __restrict__ bias,
                                                        float* __restrict__ out) {
  __shared__ u16 As[128 * 32];
  __shared__ u16 Bs[128 * 32];
  f32x4 acc[4][4] = {};
  int tid = threadIdx.x, lane = tid & 63, wid = tid >> 6;
  int wr = wid >> 1, wc = wid & 1;
  int l15 = lane & 15, g = lane >> 4;
  int rowBase = blockIdx.x * 128, colBase = blockIdx.y * 128;
  int rowS = tid >> 2, c8 = (tid & 3) << 3;

  for (int k0 = 0; k0 < 1024; k0 += 32) {
    __syncthreads();
    gload16(&A[(size_t)(rowBase + rowS) * 1024 + k0 + c8],        (char*)As + wid * 1024);
    gload16(&A[(size_t)(rowBase + 64 + rowS) * 1024 + k0 + c8],   (char*)As + 4096 + wid * 1024);
    gload16(&Bt[(size_t)(colBase + rowS) * 1024 + k0 + c8],       (char*)Bs + wid * 1024);
    gload16(&Bt[(size_t)(colBase + 64 + rowS) * 1024 + k0 + c8],  (char*)Bs + 4096 + wid * 1024);
    __syncthreads();
    bf16x8 af[4], bfv[4];
#pragma unroll
    for (int m = 0; m < 4; ++m)
      af[m] = *(const bf16x8*)&As[(wr * 64 + m * 16 + l15) * 32 + g * 8];
#pragma unroll
    for (int n = 0; n < 4; ++n)
      bfv[n] = *(const bf16x8*)&Bs[(wc * 64 + n * 16 + l15) * 32 + g * 8];
#pragma unroll
    for (int m = 0; m < 4; ++m)
#pragma unroll
      for (int n = 0; n < 4; ++n)
        acc[m][n] = MFMA(af[m], bfv[n], acc[m][n]);
  }

#pragma unroll
  for (int m = 0; m < 4; ++m)
#pragma unroll
    for (int n = 0; n < 4; ++n) {
      int colc = colBase + wc * 64 + n * 16 + l15;
      float bv = bias[colc];
#pragma unroll
      for (int j = 0; j < 4; ++j) {
        int r = rowBase + wr * 64 + m * 16 + g * 4 + j;
        out[(size_t)r * 1024 + colc] = acc[m][n][j] + bv;
      }
    }
}

extern "C" void kernel_launch(void* const* d_in, const int* in_sizes, int n_in,
                              void* d_out, int out_size, void* d_ws, size_t ws_size,
                              hipStream_t stream) {
  const float* x     = (const float*)d_in[0];
  const float* w_qkv = (const float*)d_in[1];
  const float* b_qkv = (const float*)d_in[2];
  const float* w_out = (const float*)d_in[3];
  const float* b_out = (const float*)d_in[4];
  float* out = (float*)d_out;

  char* w = (char*)d_ws;
  u16* Xb  = (u16*)(w);
  u16* W1T = (u16*)(w + (8u << 20));
  u16* W2T = (u16*)(w + (14u << 20));
  u16* Qb  = (u16*)(w + (16u << 20));
  u16* Kb  = (u16*)(w + (24u << 20));
  u16* Vtb = (u16*)(w + (32u << 20));
  u16* AO  = (u16*)(w + (40u << 20));

  // 1. cast x to bf16 (4096*1024 = 4,194,304 elems; 4/thread)
  cast_x_kernel<<<4096, 256, 0, stream>>>(x, Xb, Mrows * Cch / 4);
  // 2. transpose+cast weights to B^T (K-contiguous) layout
  transpose_cast_kernel<<<dim3(N_QKV / 32, Cch / 32), 256, 0, stream>>>(w_qkv, W1T, Cch, N_QKV);
  transpose_cast_kernel<<<dim3(Cch / 32, Cch / 32), 256, 0, stream>>>(w_out, W2T, Cch, Cch);
  // 3. QKV projection
  gemm_qkv_kernel<<<dim3(Mrows / 128, N_QKV / 128), 256, 0, stream>>>(Xb, W1T, b_qkv, Qb, Kb, Vtb);
  // 4. flash attention
  attn_kernel<<<dim3(Nc / 128, Bc * Hh), 256, 0, stream>>>(Qb, Kb, Vtb, AO);
  // 5. output projection (fp32 out + bias)
  gemm_proj_kernel<<<dim3(Mrows / 128, Cch / 128), 256, 0, stream>>>(AO, W2T, b_out, out);

  (void)in_sizes; (void)n_in; (void)out_size; (void)ws_size;
}

// Round 2
// 234.433 us; speedup vs baseline: 1.1837x; 1.1837x over previous
//
#include <hip/hip_runtime.h>

typedef unsigned short u16;
typedef __bf16 bf16x8 __attribute__((ext_vector_type(8)));
typedef __bf16 bf16x4 __attribute__((ext_vector_type(4)));
typedef float f32x4 __attribute__((ext_vector_type(4)));

#define LOG2E 1.44269504088896340736f

constexpr int Bc = 2, Nc = 2048, Cch = 1024, Hh = 16, Dd = 64;
constexpr int Mrows = Bc * Nc;        // 4096
constexpr int N_QKV = 3 * Cch;        // 3072

__device__ __forceinline__ u16 f2bf(float f) {
  unsigned int u = __float_as_uint(f);
  u += 0x7fffu + ((u >> 16) & 1u);
  return (u16)(u >> 16);
}

__device__ __forceinline__ void gload16(const void* g, void* l) {
  __builtin_amdgcn_global_load_lds((const __attribute__((address_space(1))) void*)g,
                                   (__attribute__((address_space(3))) void*)l, 16, 0, 0);
}

#define MFMA(a, b, c) __builtin_amdgcn_mfma_f32_16x16x32_bf16(a, b, c, 0, 0, 0)

// ---------------- cast x (fp32 -> bf16), 4 elems/thread ----------------
__global__ __launch_bounds__(256) void cast_x_kernel(const float* __restrict__ in,
                                                     u16* __restrict__ out, int n4) {
  int i = blockIdx.x * 256 + threadIdx.x;
  if (i >= n4) return;
  float4 v = *(const float4*)&in[i * 4];
  union { u16 h[4]; short4 s; } u;
  u.h[0] = f2bf(v.x); u.h[1] = f2bf(v.y); u.h[2] = f2bf(v.z); u.h[3] = f2bf(v.w);
  *(short4*)&out[i * 4] = u.s;
}

// ------------- transpose + cast: in fp32 [R][Cq] -> out bf16 [Cq][R] -------------
__global__ __launch_bounds__(256) void transpose_cast_kernel(const float* __restrict__ in,
                                                             u16* __restrict__ out,
                                                             int R, int Cq) {
  __shared__ float tile[32][33];
  int bx = blockIdx.x * 32;  // col base in input
  int by = blockIdx.y * 32;  // row base in input
  int tx = threadIdx.x & 31, ty = threadIdx.x >> 5;  // 32 x 8
#pragma unroll
  for (int i = 0; i < 32; i += 8)
    tile[ty + i][tx] = in[(size_t)(by + ty + i) * Cq + bx + tx];
  __syncthreads();
#pragma unroll
  for (int i = 0; i < 32; i += 8)
    out[(size_t)(bx + ty + i) * R + by + tx] = f2bf(tile[tx][ty + i]);
}

// ---------------- QKV GEMM: Xb[4096,1024] @ W1T[3072,1024]^T + b -> Q/K/Vt ----------------
// Q is pre-scaled by D^-0.5 = 0.125 here so attention needs no per-element scale.
__global__ __launch_bounds__(256) void gemm_qkv_kernel(const u16* __restrict__ A,
                                                       const u16* __restrict__ Bt,
                                                       const float* __restrict__ bias,
                                                       u16* __restrict__ Qo,
                                                       u16* __restrict__ Ko,
                                                       u16* __restrict__ Vto) {
  __shared__ u16 As[128 * 32];
  __shared__ u16 Bs[128 * 32];
  f32x4 acc[4][4] = {};
  int tid = threadIdx.x, lane = tid & 63, wid = tid >> 6;
  int wr = wid >> 1, wc = wid & 1;
  int l15 = lane & 15, g = lane >> 4;
  int rowBase = blockIdx.x * 128, colBase = blockIdx.y * 128;
  int rowS = tid >> 2, c8 = (tid & 3) << 3;

  for (int k0 = 0; k0 < 1024; k0 += 32) {
    __syncthreads();
    gload16(&A[(size_t)(rowBase + rowS) * 1024 + k0 + c8],        (char*)As + wid * 1024);
    gload16(&A[(size_t)(rowBase + 64 + rowS) * 1024 + k0 + c8],   (char*)As + 4096 + wid * 1024);
    gload16(&Bt[(size_t)(colBase + rowS) * 1024 + k0 + c8],       (char*)Bs + wid * 1024);
    gload16(&Bt[(size_t)(colBase + 64 + rowS) * 1024 + k0 + c8],  (char*)Bs + 4096 + wid * 1024);
    __syncthreads();
    bf16x8 af[4], bfv[4];
#pragma unroll
    for (int m = 0; m < 4; ++m)
      af[m] = *(const bf16x8*)&As[(wr * 64 + m * 16 + l15) * 32 + g * 8];
#pragma unroll
    for (int n = 0; n < 4; ++n)
      bfv[n] = *(const bf16x8*)&Bs[(wc * 64 + n * 16 + l15) * 32 + g * 8];
#pragma unroll
    for (int m = 0; m < 4; ++m)
#pragma unroll
      for (int n = 0; n < 4; ++n)
        acc[m][n] = MFMA(af[m], bfv[n], acc[m][n]);
  }

  // epilogue: scatter to Q [bh,n,d] (pre-scaled), K [bh,n,d], V^T [bh,d,n]  (bf16)
#pragma unroll
  for (int m = 0; m < 4; ++m)
#pragma unroll
    for (int n = 0; n < 4; ++n) {
      int colc = colBase + wc * 64 + n * 16 + l15;
      float bv = bias[colc];
      int s = colc >> 10, hd = colc & 1023;
      int h = hd >> 6, d = hd & 63;
      float scale = (s == 0) ? 0.125f : 1.0f;
#pragma unroll
      for (int j = 0; j < 4; ++j) {
        int r = rowBase + wr * 64 + m * 16 + g * 4 + j;
        int b = r >> 11, nn = r & 2047;
        u16 v = f2bf((acc[m][n][j] + bv) * scale);
        size_t bh = (size_t)(b * 16 + h);
        if (s == 0)      Qo[(bh * 2048 + nn) * 64 + d] = v;
        else if (s == 1) Ko[(bh * 2048 + nn) * 64 + d] = v;
        else             Vto[(bh * 64 + d) * 2048 + nn] = v;
      }
    }
}

// ---------------- flash attention, swapped-operand softmax ----------------
// S^T = mfma(K, Q): q lives on lane&15 -> per-lane row-local softmax (2 shfls).
// O^T = mfma(V^T, P): q stays on lane&15 -> alpha/m/l all lane-local.
__global__ __launch_bounds__(256) void attn_kernel(const u16* __restrict__ Q,
                                                   const u16* __restrict__ Km,
                                                   const u16* __restrict__ Vt,
                                                   u16* __restrict__ AO) {
  __shared__ u16 Ks[64 * 72];
  __shared__ u16 Vs[64 * 72];
  __shared__ u16 Ps[128 * 72];
  int tid = threadIdx.x, lane = tid & 63, w = tid >> 6;
  int l15 = lane & 15, g = lane >> 4;
  // XCD swizzle: linear work id = bh*16 + qt so each XCD owns 4 consecutive bh
  int bidw = (blockIdx.x & 7) * 64 + (blockIdx.x >> 3);
  int bh = bidw >> 4, qt = bidw & 15;
  int b = bh >> 4, h = bh & 15;
  const size_t base = (size_t)bh * 2048 * 64;  // same for Q/K ([bh,n,d]) and Vt ([bh,d,n])
  int qrow0 = qt * 128 + w * 32;

  bf16x8 qf[2][2];
#pragma unroll
  for (int mm = 0; mm < 2; ++mm)
#pragma unroll
    for (int ks = 0; ks < 2; ++ks)
      qf[mm][ks] = *(const bf16x8*)&Q[base + (size_t)(qrow0 + mm * 16 + l15) * 64 + ks * 32 + g * 8];

  f32x4 o[2][4] = {};
  float m_run[2] = {-1e30f, -1e30f};
  float l_run[2] = {0.f, 0.f};

  for (int nk0 = 0; nk0 < 2048; nk0 += 64) {
    // stage K tile [64 n'][64 d] and V^T tile [64 d][64 n'] (both padded to 72)
#pragma unroll
    for (int it = 0; it < 2; ++it) {
      int c = tid + it * 256;
      int rr = c >> 3, cc = (c & 7) * 8;
      *(int4*)&Ks[rr * 72 + cc] = *(const int4*)&Km[base + (size_t)(nk0 + rr) * 64 + cc];
      *(int4*)&Vs[rr * 72 + cc] = *(const int4*)&Vt[base + (size_t)rr * 2048 + nk0 + cc];
    }
    __syncthreads();

    // S^T[kv][q] = K Q^T : frag (mm,n): col(l15)=q in [mm*16..], row(g*4+j)=kv in [n*16..]
    f32x4 st[2][4] = {};
#pragma unroll
    for (int ks = 0; ks < 2; ++ks) {
      bf16x8 kf[4];
#pragma unroll
      for (int n = 0; n < 4; ++n)
        kf[n] = *(const bf16x8*)&Ks[(n * 16 + l15) * 72 + ks * 32 + g * 8];
#pragma unroll
      for (int mm = 0; mm < 2; ++mm)
#pragma unroll
        for (int n = 0; n < 4; ++n)
          st[mm][n] = MFMA(kf[n], qf[mm][ks], st[mm][n]);
    }

    // online softmax: each lane owns q-col = mm*16+l15, holds kv = n*16+g*4+j
#pragma unroll
    for (int mm = 0; mm < 2; ++mm) {
      f32x4 mx;
#pragma unroll
      for (int j = 0; j < 4; ++j)
        mx[j] = fmaxf(fmaxf(st[mm][0][j], st[mm][1][j]), fmaxf(st[mm][2][j], st[mm][3][j]));
      float mloc = fmaxf(fmaxf(mx[0], mx[1]), fmaxf(mx[2], mx[3]));
      mloc = fmaxf(mloc, __shfl_xor(mloc, 16));
      mloc = fmaxf(mloc, __shfl_xor(mloc, 32));
      float mold = m_run[mm];
      float mnew = fmaxf(mold, mloc);
      float alpha = exp2f((mold - mnew) * LOG2E);
      m_run[mm] = mnew;
      float c = mnew * LOG2E;
      f32x4 sum4 = {0.f, 0.f, 0.f, 0.f};
#pragma unroll
      for (int n = 0; n < 4; ++n) {
#pragma unroll
        for (int j = 0; j < 4; ++j)
          st[mm][n][j] = exp2f(fmaf(st[mm][n][j], LOG2E, -c));
        sum4 += st[mm][n];
      }
      float rs = (sum4[0] + sum4[1]) + (sum4[2] + sum4[3]);
      rs += __shfl_xor(rs, 16);
      rs += __shfl_xor(rs, 32);
      l_run[mm] = l_run[mm] * alpha + rs;
#pragma unroll
      for (int dn = 0; dn < 4; ++dn) o[mm][dn] *= alpha;
      // pack P -> LDS [q][kv] (4 consecutive kv per lane per n -> ds_write_b64)
#pragma unroll
      for (int n = 0; n < 4; ++n) {
        bf16x4 pv;
#pragma unroll
        for (int j = 0; j < 4; ++j) pv[j] = (__bf16)st[mm][n][j];
        *(bf16x4*)&Ps[(w * 32 + mm * 16 + l15) * 72 + n * 16 + g * 4] = pv;
      }
    }

    // O^T += V^T P^T : frag (mm,dn): col(l15)=q, row(g*4+j)=d in [dn*16..]
#pragma unroll
    for (int ks = 0; ks < 2; ++ks) {
      bf16x8 pf[2];
#pragma unroll
      for (int mm = 0; mm < 2; ++mm)
        pf[mm] = *(const bf16x8*)&Ps[(w * 32 + mm * 16 + l15) * 72 + ks * 32 + g * 8];
#pragma unroll
      for (int dn = 0; dn < 4; ++dn) {
        bf16x8 vf = *(const bf16x8*)&Vs[(dn * 16 + l15) * 72 + ks * 32 + g * 8];
#pragma unroll
        for (int mm = 0; mm < 2; ++mm)
          o[mm][dn] = MFMA(vf, pf[mm], o[mm][dn]);
      }
    }
    __syncthreads();
  }

  // epilogue: lane holds O[d = dn*16+g*4+j][q = qrow0+mm*16+l15]
#pragma unroll
  for (int mm = 0; mm < 2; ++mm) {
    float inv = 1.0f / l_run[mm];
    int nq = qrow0 + mm * 16 + l15;
    size_t rowb = ((size_t)b * 2048 + nq) * 1024 + h * 64;
#pragma unroll
    for (int dn = 0; dn < 4; ++dn) {
      bf16x4 ov;
#pragma unroll
      for (int j = 0; j < 4; ++j) ov[j] = (__bf16)(o[mm][dn][j] * inv);
      *(bf16x4*)&AO[rowb + dn * 16 + g * 4] = ov;
    }
  }
}

// ---------------- output GEMM: AO[4096,1024] @ W2T[1024,1024]^T + b -> fp32 out ----------------
__global__ __launch_bounds__(256) void gemm_proj_kernel(const u16* __restrict__ A,
                                                        const u16* __restrict__ Bt,
                                                        const float* __restrict__ bias,
                                                        float* __restrict__ out) {
  __shared__ u16 As[128 * 32];
  __shared__ u16 Bs[128 * 32];
  f32x4 acc[4][4] = {};
  int tid = threadIdx.x, lane = tid & 63, wid = tid >> 6;
  int wr = wid >> 1, wc = wid & 1;
  int l15 = lane & 15, g = lane >> 4;
  int rowBase = blockIdx.x * 128, colBase = blockIdx.y * 128;
  int rowS = tid >> 2, c8 = (tid & 3) << 3;

  for (int k0 = 0; k0 < 1024; k0 += 32) {
    __syncthreads();
    gload16(&A[(size_t)(rowBase + rowS) * 1024 + k0 + c8],        (char*)As + wid * 1024);
    gload16(&A[(size_t)(rowBase + 64 + rowS) * 1024 + k0 + c8],   (char*)As + 4096 + wid * 1024);
    gload16(&Bt[(size_t)(colBase + rowS) * 1024 + k0 + c8],       (char*)Bs + wid * 1024);
    gload16(&Bt[(size_t)(colBase + 64 + rowS) * 1024 + k0 + c8],  (char*)Bs + 4096 + wid * 1024);
    __syncthreads();
    bf16x8 af[4], bfv[4];
#pragma unroll
    for (int m = 0; m < 4; ++m)
      af[m] = *(const bf16x8*)&As[(wr * 64 + m * 16 + l15) * 32 + g * 8];
#pragma unroll
    for (int n = 0; n < 4; ++n)
      bfv[n] = *(const bf16x8*)&Bs[(wc * 64 + n * 16 + l15) * 32 + g * 8];
#pragma unroll
    for (int m = 0; m < 4; ++m)
#pragma unroll
      for (int n = 0; n < 4; ++n)
        acc[m][n] = MFMA(af[m], bfv[n], acc[m][n]);
  }

#pragma unroll
  for (int m = 0; m < 4; ++m)
#pragma unroll
    for (int n = 0; n < 4; ++n) {
      int colc = colBase + wc * 64 + n * 16 + l15;
      float bv = bias[colc];
#pragma unroll
      for (int j = 0; j < 4; ++j) {
        int r = rowBase + wr * 64 + m * 16 + g * 4 + j;
        out[(size_t)r * 1024 + colc] = acc[m][n][j] + bv;
      }
    }
}

extern "C" void kernel_launch(void* const* d_in, const int* in_sizes, int n_in,
                              void* d_out, int out_size, void* d_ws, size_t ws_size,
                              hipStream_t stream) {
  const float* x     = (const float*)d_in[0];
  const float* w_qkv = (const float*)d_in[1];
  const float* b_qkv = (const float*)d_in[2];
  const float* w_out = (const float*)d_in[3];
  const float* b_out = (const float*)d_in[4];
  float* out = (float*)d_out;

  char* w = (char*)d_ws;
  u16* Xb  = (u16*)(w);
  u16* W1T = (u16*)(w + (8u << 20));
  u16* W2T = (u16*)(w + (14u << 20));
  u16* Qb  = (u16*)(w + (16u << 20));
  u16* Kb  = (u16*)(w + (24u << 20));
  u16* Vtb = (u16*)(w + (32u << 20));
  u16* AO  = (u16*)(w + (40u << 20));

  // 1. cast x to bf16
  cast_x_kernel<<<4096, 256, 0, stream>>>(x, Xb, Mrows * Cch / 4);
  // 2. transpose+cast weights to B^T (K-contiguous) layout
  transpose_cast_kernel<<<dim3(N_QKV / 32, Cch / 32), 256, 0, stream>>>(w_qkv, W1T, Cch, N_QKV);
  transpose_cast_kernel<<<dim3(Cch / 32, Cch / 32), 256, 0, stream>>>(w_out, W2T, Cch, Cch);
  // 3. QKV projection (Q pre-scaled by 1/8)
  gemm_qkv_kernel<<<dim3(Mrows / 128, N_QKV / 128), 256, 0, stream>>>(Xb, W1T, b_qkv, Qb, Kb, Vtb);
  // 4. flash attention (1D grid, XCD-swizzled)
  attn_kernel<<<512, 256, 0, stream>>>(Qb, Kb, Vtb, AO);
  // 5. output projection (fp32 out + bias)
  gemm_proj_kernel<<<dim3(Mrows / 128, Cch / 128), 256, 0, stream>>>(AO, W2T, b_out, out);

  (void)in_sizes; (void)n_in; (void)out_size; (void)ws_size;
}